// Round 3
// baseline (274.336 us; speedup 1.0000x reference)
//
#include <hip/hip_runtime.h>

// CRF negative log-likelihood, B=8192, T=512, NT=7.
// Kernel A: each thread computes one (row, time-chunk) 7x7 linear-domain
//           transfer matrix (chunk of 32 steps) + numerator partials.
// Kernel B: one thread per row chains the 16 chunk matrices, adds start/end
//           terms, produces den - num, block-reduces, atomicAdd to out.

#define Bsz 8192
#define Tsz 512
#define NTG 7
#define NCH 16
#define CS  32   // timesteps per chunk

__device__ __forceinline__ float rfl(float x) {
    return __int_as_float(__builtin_amdgcn_readfirstlane(__float_as_int(x)));
}

__global__ __launch_bounds__(256) void crf_chunk_kernel(
    const float* __restrict__ em, const int* __restrict__ labels,
    const int* __restrict__ mask, const float* __restrict__ startT,
    const float* __restrict__ trans,
    float* __restrict__ Mbuf, float* __restrict__ lsbuf,
    float* __restrict__ numbuf, int* __restrict__ cntbuf)
{
    const int tid = blockIdx.x * blockDim.x + threadIdx.x;
    const int r = tid & (Bsz - 1);   // batch row (lane-consecutive -> coalesced ws writes)
    const int c = tid >> 13;         // chunk index (uniform per block)

    __shared__ float transS[NTG * NTG];
    if (threadIdx.x < NTG * NTG) transS[threadIdx.x] = trans[threadIdx.x];
    __syncthreads();

    // W = exp(trans), wave-uniform -> SGPRs via readfirstlane
    float W[49];
#pragma unroll
    for (int k = 0; k < 49; ++k) W[k] = rfl(__expf(trans[k]));

    // M = I
    float M[49];
#pragma unroll
    for (int k = 0; k < 49; ++k) M[k] = 0.0f;
#pragma unroll
    for (int i = 0; i < 7; ++i) M[i * 7 + i] = 1.0f;

    float logscale = 0.0f;
    float num = 0.0f;
    int   cnt = 0;

    const int t0 = c * CS;
    const float* emr  = em + (size_t)r * (Tsz * NTG) + (size_t)t0 * NTG; // 16B aligned
    const int*   labr = labels + r * Tsz + t0;
    const int*   mskr = mask   + r * Tsz + t0;

    int lprev = 0;
    if (c > 0) { lprev = labr[-1]; if (lprev < 0) lprev = 0; }

#pragma unroll 2
    for (int g = 0; g < CS / 4; ++g) {
        // 4 timesteps of emissions: 28 floats, 7x float4 (all 16B aligned)
        float4 ev[7];
        const float4* ep = (const float4*)(emr + g * (4 * NTG));
#pragma unroll
        for (int q = 0; q < 7; ++q) ev[q] = ep[q];
        const float* eraw = (const float*)&ev[0];

        int4 lab4 = *(const int4*)(labr + g * 4);
        int4 msk4 = *(const int4*)(mskr + g * 4);
        int labs[4] = {lab4.x, lab4.y, lab4.z, lab4.w};
        int msks[4] = {msk4.x, msk4.y, msk4.z, msk4.w};

#pragma unroll
        for (int s = 0; s < 4; ++s) {
            const int t = t0 + g * 4 + s;
            int lc = labs[s]; if (lc < 0) lc = 0;
            const float mf = (float)msks[s];
            cnt += msks[s];

            // gather em[t][lc] without runtime register indexing (scratch hazard)
            float esel = eraw[s * 7 + 0];
#pragma unroll
            for (int j = 1; j < 7; ++j) esel = (lc == j) ? eraw[s * 7 + j] : esel;

            if (t == 0) {
                num += startT[lc] + esel;
            } else {
                num += mf * (transS[lprev * 7 + lc] + esel);
                if (msks[s] > 0) {
                    float e[7];
#pragma unroll
                    for (int j = 0; j < 7; ++j) e[j] = __expf(eraw[s * 7 + j]);
                    // M <- M * (W . diag(e))
#pragma unroll
                    for (int i = 0; i < 7; ++i) {
                        float tmp[7];
#pragma unroll
                        for (int j = 0; j < 7; ++j) tmp[j] = 0.0f;
#pragma unroll
                        for (int k = 0; k < 7; ++k) {
                            const float mik = M[i * 7 + k];
#pragma unroll
                            for (int j = 0; j < 7; ++j)
                                tmp[j] = fmaf(mik, W[k * 7 + j], tmp[j]);
                        }
#pragma unroll
                        for (int j = 0; j < 7; ++j) M[i * 7 + j] = tmp[j] * e[j];
                    }
                }
            }
            lprev = lc;
        }

        if (g & 1) {  // rescale every 8 steps: keeps f32 in range
            float mx = 1e-30f;
#pragma unroll
            for (int k = 0; k < 49; ++k) mx = fmaxf(mx, M[k]);
            const float inv = 1.0f / mx;
#pragma unroll
            for (int k = 0; k < 49; ++k) M[k] *= inv;
            logscale += __logf(mx);
        }
    }

    // write ws: layout [c][k][r] so kernel B reads coalesced
    float* Mo = Mbuf + (size_t)c * 49 * Bsz + r;
#pragma unroll
    for (int k = 0; k < 49; ++k) Mo[k * Bsz] = M[k];
    lsbuf[c * Bsz + r]  = logscale;
    numbuf[c * Bsz + r] = num;
    cntbuf[c * Bsz + r] = cnt;
}

__global__ __launch_bounds__(256) void crf_combine_kernel(
    const float* __restrict__ em, const int* __restrict__ labels,
    const float* __restrict__ startT, const float* __restrict__ endT,
    const float* __restrict__ Mbuf, const float* __restrict__ lsbuf,
    const float* __restrict__ numbuf, const int* __restrict__ cntbuf,
    float* __restrict__ out)
{
    const int r = blockIdx.x * blockDim.x + threadIdx.x;

    // init: alpha_0 = exp(start + em[r,0,:])
    const float* em0 = em + (size_t)r * (Tsz * NTG);
    float v[7];
#pragma unroll
    for (int j = 0; j < 7; ++j) v[j] = __expf(startT[j] + em0[j]);

    float ls = 0.0f, num = 0.0f;
    int cnt = 0;

    for (int c = 0; c < NCH; ++c) {
        const float* Mc = Mbuf + (size_t)c * 49 * Bsz + r;
        float nv[7];
#pragma unroll
        for (int j = 0; j < 7; ++j) nv[j] = 0.0f;
#pragma unroll
        for (int i = 0; i < 7; ++i) {
            const float vi = v[i];
#pragma unroll
            for (int j = 0; j < 7; ++j)
                nv[j] = fmaf(vi, Mc[(i * 7 + j) * Bsz], nv[j]);
        }
        float mx = 1e-30f;
#pragma unroll
        for (int j = 0; j < 7; ++j) mx = fmaxf(mx, nv[j]);
        const float inv = 1.0f / mx;
#pragma unroll
        for (int j = 0; j < 7; ++j) v[j] = nv[j] * inv;
        ls  += __logf(mx) + lsbuf[c * Bsz + r];
        num += numbuf[c * Bsz + r];
        cnt += cntbuf[c * Bsz + r];
    }

    float dsum = 0.0f;
#pragma unroll
    for (int j = 0; j < 7; ++j) dsum += v[j] * __expf(endT[j]);
    const float den = ls + __logf(dsum);

    int se = cnt - 1; if (se < 0) se = 0;
    int lt = labels[r * Tsz + se]; if (lt < 0) lt = 0;
    num += endT[lt];

    float val = den - num;

    __shared__ float red[256];
    red[threadIdx.x] = val;
    __syncthreads();
    for (int off = 128; off > 0; off >>= 1) {
        if (threadIdx.x < off) red[threadIdx.x] += red[threadIdx.x + off];
        __syncthreads();
    }
    if (threadIdx.x == 0) atomicAdd(out, red[0]);
}

extern "C" void kernel_launch(void* const* d_in, const int* in_sizes, int n_in,
                              void* d_out, int out_size, void* d_ws, size_t ws_size,
                              hipStream_t stream) {
    const float* em     = (const float*)d_in[0];
    const int*   labels = (const int*)d_in[1];
    const int*   mask   = (const int*)d_in[2];
    const float* startT = (const float*)d_in[3];
    const float* endT   = (const float*)d_in[4];
    const float* trans  = (const float*)d_in[5];
    float* out = (float*)d_out;

    float* ws     = (float*)d_ws;
    float* Mbuf   = ws;                               // NCH*49*Bsz floats (25.7 MB)
    float* lsbuf  = Mbuf + (size_t)NCH * 49 * Bsz;    // NCH*Bsz
    float* numbuf = lsbuf + (size_t)NCH * Bsz;        // NCH*Bsz
    int*   cntbuf = (int*)(numbuf + (size_t)NCH * Bsz); // NCH*Bsz ints
    (void)in_sizes; (void)n_in; (void)out_size; (void)ws_size;

    hipMemsetAsync(out, 0, sizeof(float), stream);

    crf_chunk_kernel<<<(Bsz * NCH) / 256, 256, 0, stream>>>(
        em, labels, mask, startT, trans, Mbuf, lsbuf, numbuf, cntbuf);
    crf_combine_kernel<<<Bsz / 256, 256, 0, stream>>>(
        em, labels, startT, endT, Mbuf, lsbuf, numbuf, cntbuf, out);
}

// Round 4
// 272.187 us; speedup vs baseline: 1.0079x; 1.0079x over previous
//
#include <hip/hip_runtime.h>

// CRF NLL, B=8192, T=512, NT=7. Fused single-pass design:
// Block = 8 rows x 32 chunks (256 threads). Phase 1: each thread builds the
// 7x7 linear-domain transfer operator for its (row, 16-step chunk) + numerator
// partials, into LDS. Phase 2: each wave chains 2 rows' 32 operators via
// lane-parallel shuffles (lane k holds entry (i,j), k=i*7+j). One float per
// block to ws; tiny reduce kernel sums 1024 partials.

#define Bsz 8192
#define Tsz 512
#define NTG 7
#define NCH 32
#define CS  16
#define RPB 8
#define THB 256

__device__ __forceinline__ float rfl(float x) {
    return __int_as_float(__builtin_amdgcn_readfirstlane(__float_as_int(x)));
}

__device__ __forceinline__ float wsumf(float x) {
#pragma unroll
    for (int m = 1; m < 64; m <<= 1) x += __shfl_xor(x, m, 64);
    return x;
}
__device__ __forceinline__ int wsumi(int x) {
#pragma unroll
    for (int m = 1; m < 64; m <<= 1) x += __shfl_xor(x, m, 64);
    return x;
}
__device__ __forceinline__ float wmaxf(float x) {
#pragma unroll
    for (int m = 1; m < 64; m <<= 1) x = fmaxf(x, __shfl_xor(x, m, 64));
    return x;
}

__global__ __launch_bounds__(THB) void crf_fused_kernel(
    const float* __restrict__ em, const int* __restrict__ labels,
    const int* __restrict__ mask, const float* __restrict__ startT,
    const float* __restrict__ endT, const float* __restrict__ trans,
    float* __restrict__ blockpart)
{
    __shared__ float ldsM[THB * 49 + 20];   // pad: lanes 49..63 read OOB-of-tile
    __shared__ float ldsLs[THB];
    __shared__ float ldsNum[THB];
    __shared__ int   ldsCnt[THB];
    __shared__ float transS[52];
    __shared__ float rowval[RPB];

    const int t  = threadIdx.x;
    const int c  = t & (NCH - 1);      // chunk index
    const int rl = t >> 5;             // row-in-block 0..7
    const int r  = blockIdx.x * RPB + rl;

    if (t < 49) transS[t] = trans[t];
    __syncthreads();

    // W = exp(trans): wave-uniform -> SGPRs
    float W[49];
#pragma unroll
    for (int k = 0; k < 49; ++k) W[k] = rfl(__expf(trans[k]));

    // ---- Phase 1: per-(row,chunk) 7x7 operator over CS=16 steps ----
    float M[49];
#pragma unroll
    for (int k = 0; k < 49; ++k) M[k] = 0.0f;
#pragma unroll
    for (int i = 0; i < 7; ++i) M[i * 7 + i] = 1.0f;

    float logscale = 0.0f, num = 0.0f;
    int cnt = 0;

    const int t0 = c * CS;
    const float* emr  = em + (size_t)r * (Tsz * NTG) + (size_t)t0 * NTG; // 448B aligned
    const int*   labr = labels + r * Tsz + t0;
    const int*   mskr = mask   + r * Tsz + t0;

    int lprev = 0;
    if (c > 0) { lprev = labr[-1]; if (lprev < 0) lprev = 0; }

#pragma unroll
    for (int g = 0; g < CS / 4; ++g) {
        float4 ev[7];
        const float4* ep = (const float4*)(emr + g * 28);
#pragma unroll
        for (int q = 0; q < 7; ++q) ev[q] = ep[q];
        const float* eraw = (const float*)&ev[0];

        int4 lab4 = *(const int4*)(labr + g * 4);
        int4 msk4 = *(const int4*)(mskr + g * 4);
        int labs[4] = {lab4.x, lab4.y, lab4.z, lab4.w};
        int msks[4] = {msk4.x, msk4.y, msk4.z, msk4.w};

#pragma unroll
        for (int s = 0; s < 4; ++s) {
            const int tt = t0 + g * 4 + s;
            int lc = labs[s]; if (lc < 0) lc = 0;
            const float mf = (float)msks[s];
            cnt += msks[s];

            float esel = eraw[s * 7 + 0];
#pragma unroll
            for (int j = 1; j < 7; ++j) esel = (lc == j) ? eraw[s * 7 + j] : esel;

            if (tt == 0) {
                num += startT[lc] + esel;
            } else {
                num += mf * (transS[lprev * 7 + lc] + esel);
                if (msks[s] > 0) {
                    float e[7];
#pragma unroll
                    for (int j = 0; j < 7; ++j) e[j] = __expf(eraw[s * 7 + j]);
#pragma unroll
                    for (int i = 0; i < 7; ++i) {
                        float tmp[7];
#pragma unroll
                        for (int j = 0; j < 7; ++j) tmp[j] = 0.0f;
#pragma unroll
                        for (int k = 0; k < 7; ++k) {
                            const float mik = M[i * 7 + k];
#pragma unroll
                            for (int j = 0; j < 7; ++j)
                                tmp[j] = fmaf(mik, W[k * 7 + j], tmp[j]);
                        }
#pragma unroll
                        for (int j = 0; j < 7; ++j) M[i * 7 + j] = tmp[j] * e[j];
                    }
                }
            }
            lprev = lc;
        }
        if (g & 1) {   // rescale every 8 steps
            float mx = 1e-30f;
#pragma unroll
            for (int k = 0; k < 49; ++k) mx = fmaxf(mx, M[k]);
            const float inv = 1.0f / mx;
#pragma unroll
            for (int k = 0; k < 49; ++k) M[k] *= inv;
            logscale += __logf(mx);
        }
    }

#pragma unroll
    for (int k = 0; k < 49; ++k) ldsM[t * 49 + k] = M[k];  // stride 49: 2-way banks, free
    ldsLs[t]  = logscale;
    ldsNum[t] = num;
    ldsCnt[t] = cnt;
    __syncthreads();

    // ---- Phase 2: chain 32 operators per row; wave w owns rows 2w, 2w+1 ----
    const int lane = t & 63;
    const int wv   = t >> 6;
    const int idiv = lane / 7;     // i for entry k=i*7+j (lanes >=49: junk, masked)

    for (int rr = 0; rr < 2; ++rr) {
        const int rl2 = wv * 2 + rr;
        const int r2  = blockIdx.x * RPB + rl2;

        // v in lane-j representation: alpha_0 = exp(start + em[r,0,:])
        float v = 0.0f;
        if (lane < 7) v = __expf(startT[lane] + em[(size_t)r2 * (Tsz * NTG) + lane]);
        float ls = 0.0f;

        for (int cc = 0; cc < NCH; ++cc) {
            const float Mk = ldsM[(rl2 * NCH + cc) * 49 + lane];
            const float vi = __shfl(v, idiv, 64);
            float p = (lane < 49) ? vi * Mk : 0.0f;
            p += __shfl_down(p, 28, 64);
            p += __shfl_down(p, 14, 64);
            p += __shfl_down(p, 7, 64);
            // all lanes hold partial subsets of nv (>=0) -> global max == max_j nv[j]
            const float mx = wmaxf(p);
            v = p * (1.0f / mx);
            ls += __logf(mx);
        }

        float lsA  = (lane < NCH) ? ldsLs[rl2 * NCH + lane]  : 0.0f;
        float numA = (lane < NCH) ? ldsNum[rl2 * NCH + lane] : 0.0f;
        int   cntA = (lane < NCH) ? ldsCnt[rl2 * NCH + lane] : 0;
        ls += wsumf(lsA);
        float numt = wsumf(numA);
        int   cntt = wsumi(cntA);

        float term = (lane < 7) ? v * __expf(endT[lane]) : 0.0f;
        const float den = ls + __logf(wsumf(term));

        int se = cntt - 1; if (se < 0) se = 0;
        int lt = labels[r2 * Tsz + se]; if (lt < 0) lt = 0;
        numt += endT[lt];

        if (lane == 0) rowval[rl2] = den - numt;
    }
    __syncthreads();

    if (t == 0) {
        float s = 0.0f;
#pragma unroll
        for (int k = 0; k < RPB; ++k) s += rowval[k];
        blockpart[blockIdx.x] = s;
    }
}

__global__ __launch_bounds__(256) void crf_reduce_kernel(
    const float* __restrict__ part, float* __restrict__ out)
{
    const int t = threadIdx.x;
    float s = part[t] + part[t + 256] + part[t + 512] + part[t + 768];
    __shared__ float red[256];
    red[t] = s;
    __syncthreads();
    for (int off = 128; off > 0; off >>= 1) {
        if (t < off) red[t] += red[t + off];
        __syncthreads();
    }
    if (t == 0) out[0] = red[0];
}

extern "C" void kernel_launch(void* const* d_in, const int* in_sizes, int n_in,
                              void* d_out, int out_size, void* d_ws, size_t ws_size,
                              hipStream_t stream) {
    const float* em     = (const float*)d_in[0];
    const int*   labels = (const int*)d_in[1];
    const int*   mask   = (const int*)d_in[2];
    const float* startT = (const float*)d_in[3];
    const float* endT   = (const float*)d_in[4];
    const float* trans  = (const float*)d_in[5];
    float* out = (float*)d_out;
    float* blockpart = (float*)d_ws;   // 1024 floats
    (void)in_sizes; (void)n_in; (void)out_size; (void)ws_size;

    crf_fused_kernel<<<Bsz / RPB, THB, 0, stream>>>(
        em, labels, mask, startT, endT, trans, blockpart);
    crf_reduce_kernel<<<1, 256, 0, stream>>>(blockpart, out);
}